// Round 4
// baseline (11321.127 us; speedup 1.0000x reference)
//
#include <hip/hip_runtime.h>
#include <stdint.h>

// Problem constants
#define kS 256      // sequence length
#define kB 256      // batch
#define kE 300      // embedding dim
#define kH 300      // hidden per direction
#define kG 1200     // 4*H gate rows
#define kT 9        // tags
#define TILE_B 2    // batch rows per block
#define TCHUNK 8    // timesteps per input-projection chunk
#define RPT 5       // gate rows per thread
#define ACT 240     // active threads in GEMM phases (240*5 = 1200)

#define EMSZ (kS * kB * kT)   // floats per direction of emission buffer
#define W4   (kG * 75)        // float4 count per transposed weight matrix

// NOTE: must be a function, not a macro — a macro param named `w` would
// capture the `.w` member token in its own body (R3 compile failure).
__device__ __forceinline__ void fma4(float& acc, const float4& wv, const float4& av) {
    acc += wv.x * av.x + wv.y * av.y + wv.z * av.z + wv.w * av.w;
}

__device__ __forceinline__ float sigmoidf_(float v) { return 1.0f / (1.0f + expf(-v)); }

// -----------------------------------------------------------------------------
// Pre-pass: transpose [1200][300] weights into k-major float4 layout
// wt[k4*1200 + r] = w[r][4k4..4k4+3] -> coalesced 1KB-per-wave loads in GEMM.
// -----------------------------------------------------------------------------
__global__ __launch_bounds__(256) void transpose_w(const float* __restrict__ w,
                                                   float4* __restrict__ wt) {
    int i = blockIdx.x * 256 + threadIdx.x;
    if (i >= W4) return;
    int k4 = i / kG;
    int r  = i - k4 * kG;
    const float* p = w + (size_t)r * 300 + k4 * 4;
    wt[i] = make_float4(p[0], p[1], p[2], p[3]);
}

// -----------------------------------------------------------------------------
// Fused BiLSTM. One block = (direction, 2-batch-row tile); h,c in LDS for all
// 256 steps. w_hh streamed from L2 with double-buffered 5-kc groups (25
// in-flight 16B loads/wave). Next chunk's input projection is accumulated in
// registers *inside* the feed-bound hh loop, overlapping the w_ih stream with
// the w_hh stream. Emissions (fp32) to workspace.
// -----------------------------------------------------------------------------
__global__ __launch_bounds__(256, 1) void ner_bilstm_kernel(
    const int*    __restrict__ x,        // [B][S]
    const float*  __restrict__ emb,      // [V][E]
    const float4* __restrict__ wih4_f,   // k-major [75][1200] float4
    const float4* __restrict__ whh4_f,
    const float*  __restrict__ bih_f,
    const float*  __restrict__ bhh_f,
    const float4* __restrict__ wih4_b,
    const float4* __restrict__ whh4_b,
    const float*  __restrict__ bih_b,
    const float*  __restrict__ bhh_b,
    const float*  __restrict__ w_proj,   // [9][600]
    float*        __restrict__ em_all)   // ws: em_f then em_b, each [S][B][9]
{
    extern __shared__ float s_pre[];                 // [16][1200] = 76.8 KB dynamic
    __shared__ float s_Ax[2][TCHUNK * TILE_B][304];  // double-buffered x chunks
    __shared__ float s_h[TILE_B][304];
    __shared__ float s_c[TILE_B][304];
    __shared__ float s_gbuf[TILE_B][kG];
    __shared__ float s_emp[TILE_B][kT][14];

    const int bi   = blockIdx.x;
    const int xcd  = bi & 7;
    const int dir  = (xcd >= 4) ? 1 : 0;             // XCD-grouped: 1 dir per XCD-half
    const int tile = (bi >> 3) * 4 + (xcd & 3);      // 0..127

    const float4* wih4 = dir ? wih4_b : wih4_f;
    const float4* whh4 = dir ? whh4_b : whh4_f;
    const float*  bih  = dir ? bih_b  : bih_f;
    const float*  bhh  = dir ? bhh_b  : bhh_f;
    float* emout = em_all + (size_t)dir * EMSZ;

    const int tid = threadIdx.x;

    float bsum[RPT];
    if (tid < ACT) {
#pragma unroll
        for (int j = 0; j < RPT; ++j) bsum[j] = bih[tid + j * ACT] + bhh[tid + j * ACT];
    }

    for (int i = tid; i < TILE_B * 304; i += 256) { (&s_h[0][0])[i] = 0.0f; (&s_c[0][0])[i] = 0.0f; }

    // ---- embedding gather helper ----------------------------------------------
    auto gather = [&](int tc, int buf) {
        const int rr = tid >> 4, ln = tid & 15;
        const int tt = rr >> 1, b2 = rr & 1;
        const int t  = tc * TCHUNK + tt;
        const int s  = dir ? (kS - 1 - t) : t;
        const int bg = tile * TILE_B + b2;
        const int token = x[bg * kS + s];
        const float* erow = emb + (size_t)token * kE;
        for (int e = ln; e < kE; e += 16) s_Ax[buf][rr][e] = erow[e];
    };

    // ---- pre-pass: chunk 0 input projection (simple burst) ---------------------
    gather(0, 0);
    __syncthreads();
    if (tid < ACT) {
        float acc[RPT][16];
#pragma unroll
        for (int j = 0; j < RPT; ++j)
#pragma unroll
            for (int q = 0; q < 16; ++q) acc[j][q] = bsum[j];
        const float4* wp = wih4 + tid;
        for (int kc = 0; kc < 75; ++kc) {
            float4 wv[RPT];
#pragma unroll
            for (int j = 0; j < RPT; ++j) wv[j] = wp[kc * kG + j * ACT];
#pragma unroll
            for (int q = 0; q < 16; ++q) {
                const float4 a = *(const float4*)&s_Ax[0][q][kc * 4];
#pragma unroll
                for (int j = 0; j < RPT; ++j) fma4(acc[j][q], wv[j], a);
            }
        }
#pragma unroll
        for (int j = 0; j < RPT; ++j)
#pragma unroll
            for (int q = 0; q < 16; ++q) s_pre[q * kG + tid + j * ACT] = acc[j][q];
    }
    __syncthreads();
    gather(1, 1);
    __syncthreads();

    // ---- main loop over 32 chunks ---------------------------------------------
    for (int tc = 0; tc < kS / TCHUNK; ++tc) {
        if (tc + 2 < kS / TCHUNK) gather(tc + 2, tc & 1);   // consumers past next barrier
        const int  nb    = (tc + 1) & 1;                    // x-buffer of next chunk
        const bool do_ih = (tc + 1 < kS / TCHUNK);

        float acc_ih[RPT][16];
        float4 wib[RPT];
        int ihk = 0;
        if (tid < ACT && do_ih) {
#pragma unroll
            for (int j = 0; j < RPT; ++j) {
#pragma unroll
                for (int q = 0; q < 16; ++q) acc_ih[j][q] = bsum[j];
                wib[j] = wih4[tid + j * ACT];               // preload ihk=0
            }
        }

        for (int tt = 0; tt < TCHUNK; ++tt) {
            const int t = tc * TCHUNK + tt;
            const int s = dir ? (kS - 1 - t) : t;

            // ---- hh-GEMM (double-buffered 5-kc groups) + interleaved ih --------
            if (tid < ACT) {
                float acc0[RPT], acc1[RPT];
#pragma unroll
                for (int j = 0; j < RPT; ++j) {
                    acc0[j] = s_pre[(tt * 2 + 0) * kG + tid + j * ACT];
                    acc1[j] = s_pre[(tt * 2 + 1) * kG + tid + j * ACT];
                }
                const float4* wp = whh4 + tid;
                float4 buf[2][25];
#pragma unroll
                for (int k = 0; k < 5; ++k)
#pragma unroll
                    for (int j = 0; j < RPT; ++j) buf[0][k * 5 + j] = wp[k * kG + j * ACT];

#pragma unroll 2
                for (int g = 0; g < 15; ++g) {
                    const int cb = g & 1, nf = (g + 1) & 1;
                    if (g < 14) {
#pragma unroll
                        for (int k = 0; k < 5; ++k)
#pragma unroll
                            for (int j = 0; j < RPT; ++j)
                                buf[nf][k * 5 + j] = wp[((g + 1) * 5 + k) * kG + j * ACT];
                    }
#pragma unroll
                    for (int k = 0; k < 5; ++k) {
                        const int kc = g * 5 + k;
                        const float4 a0 = *(const float4*)&s_h[0][kc * 4];
                        const float4 a1 = *(const float4*)&s_h[1][kc * 4];
#pragma unroll
                        for (int j = 0; j < RPT; ++j) {
                            const float4 wv = buf[cb][k * 5 + j];
                            fma4(acc0[j], wv, a0);
                            fma4(acc1[j], wv, a1);
                        }
                    }
                    // ih pacing: 75 ih-kcs spread over 120 groups (5/8 per group)
                    if (do_ih) {
                        const int target = ((tt * 15 + g + 1) * 5) >> 3;
                        if (ihk < target) {
#pragma unroll
                            for (int q = 0; q < 16; ++q) {
                                const float4 a = *(const float4*)&s_Ax[nb][q][ihk * 4];
#pragma unroll
                                for (int j = 0; j < RPT; ++j) fma4(acc_ih[j][q], wib[j], a);
                            }
                            ++ihk;
                            const int lk = (ihk < 75) ? ihk : 74;
#pragma unroll
                            for (int j = 0; j < RPT; ++j) wib[j] = wih4[lk * kG + tid + j * ACT];
                        }
                    }
                }
#pragma unroll
                for (int j = 0; j < RPT; ++j) {
                    s_gbuf[0][tid + j * ACT] = acc0[j];
                    s_gbuf[1][tid + j * ACT] = acc1[j];
                }
            }
            __syncthreads();

            // ---- LSTM cell update (gate order i,f,g,o) -------------------------
#pragma unroll
            for (int rep = 0; rep < 2; ++rep) {
                const int nn = tid + rep * 256;
                if (nn < kH) {
#pragma unroll
                    for (int b2 = 0; b2 < TILE_B; ++b2) {
                        const float gi = s_gbuf[b2][nn];
                        const float gf = s_gbuf[b2][nn + 300];
                        const float gg = s_gbuf[b2][nn + 600];
                        const float go = s_gbuf[b2][nn + 900];
                        const float c  = sigmoidf_(gf) * s_c[b2][nn] + sigmoidf_(gi) * tanhf(gg);
                        const float h  = sigmoidf_(go) * tanhf(c);
                        s_c[b2][nn] = c;
                        s_h[b2][nn] = h;
                    }
                }
            }
            __syncthreads();

            // ---- emissions -----------------------------------------------------
            if (tid < 252) {
                const int b2  = tid / 126;
                const int rem = tid % 126;
                const int tag = rem / 14;
                const int ch  = rem % 14;
                const int n0  = ch * 22;
                const int n1  = (n0 + 22 < 300) ? n0 + 22 : 300;
                const float* wrow = w_proj + tag * (2 * kH) + dir * kH;
                float sum = 0.0f;
                for (int n = n0; n < n1; ++n) sum += s_h[b2][n] * wrow[n];
                s_emp[b2][tag][ch] = sum;
            }
            __syncthreads();

            if (tid < TILE_B * kT) {
                const int b2  = tid / kT;
                const int tag = tid % kT;
                float sum = 0.0f;
#pragma unroll
                for (int ch = 0; ch < 14; ++ch) sum += s_emp[b2][tag][ch];
                const int bg = tile * TILE_B + b2;
                emout[((size_t)s * kB + bg) * kT + tag] = sum;
            }
        }

        // ---- chunk end: publish next chunk's pre-activations -------------------
        if (do_ih && tid < ACT) {
#pragma unroll
            for (int j = 0; j < RPT; ++j)
#pragma unroll
                for (int q = 0; q < 16; ++q) s_pre[q * kG + tid + j * ACT] = acc_ih[j][q];
        }
        __syncthreads();
    }
}

// -----------------------------------------------------------------------------
// CRF Viterbi decode. 9 lanes per batch row; shuffle-based max; first-max
// tie-breaking matches np.argmax.
// -----------------------------------------------------------------------------
__global__ __launch_bounds__(256) void ner_viterbi_kernel(
    const float* __restrict__ em_all,
    const float* __restrict__ b_proj,
    const float* __restrict__ start_t,
    const float* __restrict__ end_t,
    const float* __restrict__ trans,
    int*         __restrict__ out)
{
    const float* em_f = em_all;
    const float* em_b = em_all + EMSZ;

    __shared__ uint8_t bp[kS - 1][28][kT];

    const int tid  = threadIdx.x;
    const int wave = tid >> 6;
    const int lane = tid & 63;
    const int g    = lane / kT;
    const int nx   = lane % kT;
    const bool active = (g < 7);
    const int gg   = wave * 7 + g;
    const int b    = blockIdx.x * 28 + (active ? gg : 0);
    const bool valid = active && (b < kB);
    const int beff = (b < kB) ? b : (kB - 1);
    const int base = g * kT;

    float tcol[kT];
#pragma unroll
    for (int p = 0; p < kT; ++p) tcol[p] = trans[p * kT + nx];
    const float bpj = b_proj[nx];

    float score = start_t[nx]
                + em_f[(size_t)beff * kT + nx]
                + em_b[(size_t)beff * kT + nx]
                + bpj;

    for (int t = 1; t < kS; ++t) {
        const size_t ei = ((size_t)t * kB + beff) * kT + nx;
        const float em = em_f[ei] + em_b[ei] + bpj;
        float best = -3.402823466e38f;
        int bidx = 0;
#pragma unroll
        for (int p = 0; p < kT; ++p) {
            const float sp = __shfl(score, base + p, 64);
            const float cand = sp + tcol[p];
            if (cand > best) { best = cand; bidx = p; }
        }
        if (valid) bp[t - 1][gg][nx] = (uint8_t)bidx;
        score = best + em;
    }

    score += end_t[nx];
    float best = -3.402823466e38f;
    int last = 0;
#pragma unroll
    for (int p = 0; p < kT; ++p) {
        const float sp = __shfl(score, base + p, 64);
        if (sp > best) { best = sp; last = p; }
    }

    __syncthreads();

    if (valid && nx == 0) {
        int cur = last;
        out[beff * kS + (kS - 1)] = cur;
        for (int t = kS - 2; t >= 0; --t) {
            cur = bp[t][gg][cur];
            out[beff * kS + t] = cur;
        }
    }
}

// -----------------------------------------------------------------------------
extern "C" void kernel_launch(void* const* d_in, const int* in_sizes, int n_in,
                              void* d_out, int out_size, void* d_ws, size_t ws_size,
                              hipStream_t stream) {
    const int*   x       = (const int*)  d_in[0];
    const float* emb     = (const float*)d_in[1];
    const float* w_ih_f  = (const float*)d_in[2];
    const float* w_hh_f  = (const float*)d_in[3];
    const float* b_ih_f  = (const float*)d_in[4];
    const float* b_hh_f  = (const float*)d_in[5];
    const float* w_ih_b  = (const float*)d_in[6];
    const float* w_hh_b  = (const float*)d_in[7];
    const float* b_ih_b  = (const float*)d_in[8];
    const float* b_hh_b  = (const float*)d_in[9];
    const float* w_proj  = (const float*)d_in[10];
    const float* b_proj  = (const float*)d_in[11];
    const float* start_t = (const float*)d_in[12];
    const float* end_t   = (const float*)d_in[13];
    const float* trans   = (const float*)d_in[14];

    // workspace: em (4.72 MB) | 4 transposed weight matrices (5.76 MB)
    float*  em_all  = (float*)d_ws;
    float4* wt_base = (float4*)((char*)d_ws + (size_t)2 * EMSZ * 4);
    float4* wt_ihf  = wt_base;
    float4* wt_hhf  = wt_base + W4;
    float4* wt_ihb  = wt_base + 2 * W4;
    float4* wt_hhb  = wt_base + 3 * W4;

    const int tgrid = (W4 + 255) / 256;
    transpose_w<<<tgrid, 256, 0, stream>>>(w_ih_f, wt_ihf);
    transpose_w<<<tgrid, 256, 0, stream>>>(w_hh_f, wt_hhf);
    transpose_w<<<tgrid, 256, 0, stream>>>(w_ih_b, wt_ihb);
    transpose_w<<<tgrid, 256, 0, stream>>>(w_hh_b, wt_hhb);

    ner_bilstm_kernel<<<256, 256, 16 * kG * sizeof(float), stream>>>(
        x, emb, wt_ihf, wt_hhf, b_ih_f, b_hh_f,
        wt_ihb, wt_hhb, b_ih_b, b_hh_b, w_proj, em_all);

    ner_viterbi_kernel<<<10, 256, 0, stream>>>(
        em_all, b_proj, start_t, end_t, trans, (int*)d_out);
}